// Round 10
// baseline (293.855 us; speedup 1.0000x reference)
//
#include <hip/hip_runtime.h>

// GNN_41051297415239: 2-layer GraphSAGE + linear skip on MI355X (gfx950)
// N=100000 nodes, E=1600000 edges, F_IN=64, HID=128, OUT=64
//
// R9 -> R10 (2 changes, both occupancy/latency):
//  1. gemmF-v2: W1 fragments read from global (like W2 already was); LDS
//     is hs only (17 KB, was 52 KB) -> blocks/CU 3 -> 6-7, staging loop +
//     barrier gone. (R9: MfmaUtil 5%, occupancy 23% -- latency-bound.)
//  2. super-bucket CSR: 98 buckets x 1024 dsts. bscatter runs per
//     (block,SB) = ~64 edges = 4 full lines (was 8 edges/32B: WRITE 30MB,
//     occupancy 8.8%); csr_build = 98 blocks x 512thr, 1024-counter LDS
//     hist+scan, csr writes block-local (single XCD window).
//
// Algebra:
//   h   = relu( [mean1 | x] @ [W1n ; W1r+Wl1] + (b1n+bl1) )   (K=128 GEMM)
//   p   = h @ W2n        (project BEFORE aggregating: 64-wide gather)
//   out = mean(p) + h @ (W2r+Wl2) + (b2n+bl2)

#define NN 100000
#define NE 1600000
#define NSB 98          // ceil(NN/1024) super-buckets
#define CAP2 18432      // padded SB capacity (mean 16384, +16 sigma)
#define EPB 6250        // edges per bscatter block (256 blocks)

typedef __attribute__((ext_vector_type(8))) __bf16 bf16x8;
typedef __attribute__((ext_vector_type(4))) float f32x4;

__device__ __forceinline__ float b2f(unsigned short u) {
    unsigned v = ((unsigned)u) << 16;
    float f;
    __builtin_memcpy(&f, &v, 4);
    return f;
}
__device__ __forceinline__ float b2f_lo(unsigned v) {
    unsigned w = v << 16;
    float f;
    __builtin_memcpy(&f, &w, 4);
    return f;
}
__device__ __forceinline__ float b2f_hi(unsigned v) {
    unsigned w = v & 0xFFFF0000u;
    float f;
    __builtin_memcpy(&f, &w, 4);
    return f;
}
__device__ __forceinline__ unsigned short f2b(float f) {
    unsigned u;
    __builtin_memcpy(&u, &f, 4);
    u += 0x7FFFu + ((u >> 16) & 1u);   // round-to-nearest-even
    return (unsigned short)(u >> 16);
}

// flags[0] = 1 if edge_index is int64; flags[1] = 1 if x/weights are fp32.
__global__ void sniff_kernel(const int* __restrict__ ei,
                             const unsigned int* __restrict__ xw,
                             int* __restrict__ flags) {
    __shared__ int s_or[256];
    __shared__ int s_cnt[256];
    int tid = threadIdx.x;
    s_or[tid] = ei[2 * tid + 1];
    unsigned e = (xw[tid] >> 7) & 0xFFu;
    s_cnt[tid] = (e > 0x85u) ? 1 : 0;
    __syncthreads();
    for (int s = 128; s > 0; s >>= 1) {
        if (tid < s) { s_or[tid] |= s_or[tid + s]; s_cnt[tid] += s_cnt[tid + s]; }
        __syncthreads();
    }
    if (tid == 0) {
        flags[0] = (s_or[0] == 0) ? 1 : 0;
        flags[1] = (s_cnt[0] >= 32) ? 1 : 0;
    }
}

// Canonicalize x -> bf16, 8 elements per thread (32B read / 16B write).
__global__ __launch_bounds__(256) void conv_x_kernel(
    const void* __restrict__ x, const int* __restrict__ flags,
    unsigned int* __restrict__ xbu) {
    int t = blockIdx.x * 256 + threadIdx.x;
    if (t >= NN * 8) return;
    if (flags[1]) {
        const float4* xf = (const float4*)x;
        float4 a = xf[2 * t], b = xf[2 * t + 1];
        uint4 o;
        o.x = f2b(a.x) | ((unsigned)f2b(a.y) << 16);
        o.y = f2b(a.z) | ((unsigned)f2b(a.w) << 16);
        o.z = f2b(b.x) | ((unsigned)f2b(b.y) << 16);
        o.w = f2b(b.z) | ((unsigned)f2b(b.w) << 16);
        ((uint4*)xbu)[t] = o;
    } else {
        ((uint4*)xbu)[t] = ((const uint4*)x)[t];
    }
}

// Combined transposed bf16 weights + fp32 biases.
__global__ __launch_bounds__(256) void prep_w_kernel(
    const int* __restrict__ flags,
    const void* W1n, const void* W1r, const void* Wl1,
    const void* b1n, const void* bl1,
    const void* W2n, const void* W2r, const void* Wl2,
    const void* b2n, const void* bl2,
    unsigned short* __restrict__ Wt1g, unsigned short* __restrict__ Wt2g,
    float* __restrict__ bias1, float* __restrict__ bias2) {
    bool fp32 = flags[1] != 0;
    auto rd = [&](const void* p, int i) -> float {
        return fp32 ? ((const float*)p)[i] : b2f(((const unsigned short*)p)[i]);
    };
    int tid = threadIdx.x;
    if (blockIdx.x == 0) {
        for (int idx = tid; idx < 128 * 128; idx += 256) {
            int k = idx >> 7, c = idx & 127;
            float v = (k < 64) ? rd(W1n, k * 128 + c)
                               : rd(W1r, (k - 64) * 128 + c) + rd(Wl1, (k - 64) * 128 + c);
            Wt1g[c * 128 + k] = f2b(v);
        }
        for (int c = tid; c < 128; c += 256) bias1[c] = rd(b1n, c) + rd(bl1, c);
    } else {
        for (int idx = tid; idx < 128 * 128; idx += 256) {
            int k = idx >> 7, c = idx & 127;
            float v = (c < 64) ? rd(W2n, k * 64 + c)
                               : rd(W2r, k * 64 + (c - 64)) + rd(Wl2, k * 64 + (c - 64));
            Wt2g[c * 128 + k] = f2b(v);
        }
        for (int c = tid; c < 64; c += 256) bias2[c] = rd(b2n, c) + rd(bl2, c);
    }
}

// --- Super-bucket CSR build (once, shared by both agg passes) ---
// cntP: one cursor per 64B line (index sb*16), zeroed beforehand.
// SB sb's window: ebuf/csr [sb*CAP2, sb*CAP2 + cnt_sb).

__global__ __launch_bounds__(512) void bscatter_kernel(
    const int* __restrict__ ei, const int* __restrict__ flags,
    int* __restrict__ cntP, int* __restrict__ ebuf) {
    __shared__ int lh[NSB];     // counts, then rank cursor
    __shared__ int lbase[NSB];  // this block's reserved base within SB
    int t = threadIdx.x;
    if (t < NSB) lh[t] = 0;
    __syncthreads();
    int e0 = blockIdx.x * EPB;
    bool i64 = flags[0] != 0;
    for (int i = t; i < EPB; i += 512) {
        int e = e0 + i;
        int d = i64 ? (int)((const long long*)ei)[NE + e] : ei[NE + e];
        atomicAdd(&lh[d >> 10], 1);
    }
    __syncthreads();
    if (t < NSB) {
        int c = lh[t];
        lbase[t] = c ? atomicAdd(&cntP[t * 16], c) : 0;
        lh[t] = 0;
    }
    __syncthreads();
    for (int i = t; i < EPB; i += 512) {
        int e = e0 + i;
        int s, d;
        if (i64) { const long long* q = (const long long*)ei; s = (int)q[e]; d = (int)q[NE + e]; }
        else     { s = ei[e]; d = ei[NE + e]; }
        int sb = d >> 10;
        int r = lbase[sb] + atomicAdd(&lh[sb], 1);
        if (r < CAP2) ebuf[sb * CAP2 + r] = (s << 10) | (d & 1023);
    }
}

// One block (512 thr) per super-bucket: 1024-counter LDS hist + scan ->
// rpack[d] = (abs_start<<8)|deg, dst-sorted csr into the SB's dense
// window (block-local writes: single XCD, no false sharing).
__global__ __launch_bounds__(512) void csr_build_kernel(
    const int* __restrict__ ebuf, const int* __restrict__ cntP,
    int* __restrict__ rpack, int* __restrict__ csr) {
    __shared__ int lcnt[1024];
    __shared__ int lsum[512];
    __shared__ int lcur[1024];
    int t = threadIdx.x, b = blockIdx.x;
    lcnt[t] = 0; lcnt[t + 512] = 0;
    __syncthreads();
    int base = b * CAP2;
    int cnt = min(cntP[b * 16], CAP2);
    for (int i = t; i < cnt; i += 512) atomicAdd(&lcnt[ebuf[base + i] & 1023], 1);
    __syncthreads();
    int c0 = lcnt[2 * t], c1 = lcnt[2 * t + 1];
    lsum[t] = c0 + c1;
    __syncthreads();
    for (int off = 1; off < 512; off <<= 1) {   // Hillis-Steele inclusive
        int v = lsum[t];
        int add = (t >= off) ? lsum[t - off] : 0;
        __syncthreads();
        lsum[t] = v + add;
        __syncthreads();
    }
    int excl = (t == 0) ? 0 : lsum[t - 1];
    int ex0 = excl, ex1 = excl + c0;
    lcur[2 * t] = ex0; lcur[2 * t + 1] = ex1;
    int d0 = b * 1024 + 2 * t;
    if (d0 < NN)     rpack[d0]     = ((base + ex0) << 8) | min(c0, 255);
    if (d0 + 1 < NN) rpack[d0 + 1] = ((base + ex1) << 8) | min(c1, 255);
    __syncthreads();
    for (int i = t; i < cnt; i += 512) {
        int pk = ebuf[base + i];
        int r = atomicAdd(&lcur[pk & 1023], 1);
        csr[base + r] = pk >> 10;
    }
}

// --- Slot-per-dst gather: wave = 8 dsts, 8 lanes/dst, 16B row-loads ---
// Quad loop with UNCONDITIONAL loads: 4 rows in flight per slot.

// Layer-1 aggregation: write bf16 mean1[N,64].
__global__ __launch_bounds__(256) void agg1_kernel(
    const unsigned short* __restrict__ feat, const int* __restrict__ rpack,
    const int* __restrict__ csr, unsigned int* __restrict__ mean1u) {
    int wid = threadIdx.x >> 6, lane = threadIdx.x & 63;
    int slot = lane >> 3, fo = (lane & 7) * 8;
    int d = (blockIdx.x * 4 + wid) * 8 + slot;
    int dd = min(d, NN - 1);
    int rp = rpack[dd];
    int base = rp >> 8;
    int deg = rp & 255;
    float acc[8];
#pragma unroll
    for (int k = 0; k < 8; ++k) acc[k] = 0.f;
    int t = 0;
    for (; t + 4 <= deg; t += 4) {
        int i0 = csr[base + t], i1 = csr[base + t + 1];
        int i2 = csr[base + t + 2], i3 = csr[base + t + 3];
        bf16x8 v0 = *(const bf16x8*)(feat + (size_t)i0 * 64 + fo);
        bf16x8 v1 = *(const bf16x8*)(feat + (size_t)i1 * 64 + fo);
        bf16x8 v2 = *(const bf16x8*)(feat + (size_t)i2 * 64 + fo);
        bf16x8 v3 = *(const bf16x8*)(feat + (size_t)i3 * 64 + fo);
#pragma unroll
        for (int k = 0; k < 8; ++k)
            acc[k] += ((float)v0[k] + (float)v1[k]) + ((float)v2[k] + (float)v3[k]);
    }
    for (; t < deg; ++t) {
        int i = csr[base + t];
        bf16x8 v = *(const bf16x8*)(feat + (size_t)i * 64 + fo);
#pragma unroll
        for (int k = 0; k < 8; ++k) acc[k] += (float)v[k];
    }
    if (d < NN) {
        float r = 1.0f / fmaxf((float)deg, 1.0f);
        uint4 o;
        o.x = f2b(acc[0] * r) | ((unsigned)f2b(acc[1] * r) << 16);
        o.y = f2b(acc[2] * r) | ((unsigned)f2b(acc[3] * r) << 16);
        o.z = f2b(acc[4] * r) | ((unsigned)f2b(acc[5] * r) << 16);
        o.w = f2b(acc[6] * r) | ((unsigned)f2b(acc[7] * r) << 16);
        *(uint4*)(mean1u + (size_t)d * 32 + (lane & 7) * 4) = o;
    }
}

// Layer-2 aggregation fused with final epilogue:
// out = mean(p) + sf + bias2  (store fp32 or bf16 per flags[1]).
__global__ __launch_bounds__(256) void agg2_kernel(
    const unsigned short* __restrict__ p, const int* __restrict__ rpack,
    const int* __restrict__ csr, const unsigned int* __restrict__ sfu,
    const float* __restrict__ bias2, const int* __restrict__ flags,
    void* __restrict__ out) {
    int wid = threadIdx.x >> 6, lane = threadIdx.x & 63;
    int slot = lane >> 3, fo = (lane & 7) * 8;
    int d = (blockIdx.x * 4 + wid) * 8 + slot;
    int dd = min(d, NN - 1);
    int rp = rpack[dd];
    int base = rp >> 8;
    int deg = rp & 255;
    float acc[8];
#pragma unroll
    for (int k = 0; k < 8; ++k) acc[k] = 0.f;
    int t = 0;
    for (; t + 4 <= deg; t += 4) {
        int i0 = csr[base + t], i1 = csr[base + t + 1];
        int i2 = csr[base + t + 2], i3 = csr[base + t + 3];
        bf16x8 v0 = *(const bf16x8*)(p + (size_t)i0 * 64 + fo);
        bf16x8 v1 = *(const bf16x8*)(p + (size_t)i1 * 64 + fo);
        bf16x8 v2 = *(const bf16x8*)(p + (size_t)i2 * 64 + fo);
        bf16x8 v3 = *(const bf16x8*)(p + (size_t)i3 * 64 + fo);
#pragma unroll
        for (int k = 0; k < 8; ++k)
            acc[k] += ((float)v0[k] + (float)v1[k]) + ((float)v2[k] + (float)v3[k]);
    }
    for (; t < deg; ++t) {
        int i = csr[base + t];
        bf16x8 v = *(const bf16x8*)(p + (size_t)i * 64 + fo);
#pragma unroll
        for (int k = 0; k < 8; ++k) acc[k] += (float)v[k];
    }
    if (d < NN) {
        float r = 1.0f / fmaxf((float)deg, 1.0f);
        uint4 sv = *(const uint4*)(sfu + (size_t)d * 32 + (lane & 7) * 4);
        float4 bA = *(const float4*)(bias2 + fo);
        float4 bB = *(const float4*)(bias2 + fo + 4);
        float v0 = acc[0] * r + b2f_lo(sv.x) + bA.x;
        float v1 = acc[1] * r + b2f_hi(sv.x) + bA.y;
        float v2 = acc[2] * r + b2f_lo(sv.y) + bA.z;
        float v3 = acc[3] * r + b2f_hi(sv.y) + bA.w;
        float v4 = acc[4] * r + b2f_lo(sv.z) + bB.x;
        float v5 = acc[5] * r + b2f_hi(sv.z) + bB.y;
        float v6 = acc[6] * r + b2f_lo(sv.w) + bB.z;
        float v7 = acc[7] * r + b2f_hi(sv.w) + bB.w;
        if (flags[1]) {
            float* op = (float*)out + (size_t)d * 64 + fo;
            *(float4*)op = make_float4(v0, v1, v2, v3);
            *(float4*)(op + 4) = make_float4(v4, v5, v6, v7);
        } else {
            uint4 o;
            o.x = f2b(v0) | ((unsigned)f2b(v1) << 16);
            o.y = f2b(v2) | ((unsigned)f2b(v3) << 16);
            o.z = f2b(v4) | ((unsigned)f2b(v5) << 16);
            o.w = f2b(v6) | ((unsigned)f2b(v7) << 16);
            *(uint4*)((unsigned int*)out + (size_t)d * 32 + (lane & 7) * 4) = o;
        }
    }
}

// Fused GEMM v2: phase 1 computes h = relu([mean1|xb]@W1t + b1) into a
// per-wave LDS tile (no barrier: each wave reads back only its own 16
// rows); phase 2 computes p = h@W2n and sf = h@(W2r+Wl2). W1 AND W2
// fragments are read straight from global (32 KB each, L1/L2-resident)
// -- LDS is hs only (17 KB) for high occupancy.
__global__ __launch_bounds__(256, 6) void gemmF_kernel(
    const unsigned short* __restrict__ mean1,
    const unsigned short* __restrict__ xb,
    const unsigned short* __restrict__ Wt1g, const float* __restrict__ bias1,
    const unsigned short* __restrict__ Wt2g,
    unsigned short* __restrict__ p, unsigned short* __restrict__ sf) {
    __shared__ unsigned short hs[64 * 136];    // h tile: 64 rows x 128 cols
    int tid = threadIdx.x;
    int wid = tid >> 6, lane = tid & 63;
    int m = lane & 15, g = lane >> 4;
    int row0 = blockIdx.x * 64 + wid * 16;
    int arow = min(row0 + m, NN - 1);

    f32x4 acc[8];
#pragma unroll
    for (int nt = 0; nt < 8; ++nt) acc[nt] = (f32x4){0.f, 0.f, 0.f, 0.f};

#pragma unroll
    for (int kt = 0; kt < 4; ++kt) {
        int k0 = kt * 32 + g * 8;
        bf16x8 a = (k0 < 64)
            ? *(const bf16x8*)(mean1 + (size_t)arow * 64 + k0)
            : *(const bf16x8*)(xb + (size_t)arow * 64 + (k0 - 64));
#pragma unroll
        for (int nt = 0; nt < 8; ++nt) {
            bf16x8 b = *(const bf16x8*)(&Wt1g[(nt * 16 + m) * 128 + k0]);
            acc[nt] = __builtin_amdgcn_mfma_f32_16x16x32_bf16(a, b, acc[nt], 0, 0, 0);
        }
    }

    // phase-1 epilogue: relu+bias -> hs (wave's own 16-row slice)
#pragma unroll
    for (int nt = 0; nt < 8; ++nt) {
        int col = nt * 16 + m;
        float bias = bias1[col];
#pragma unroll
        for (int r = 0; r < 4; ++r) {
            float v = fmaxf(acc[nt][r] + bias, 0.0f);
            hs[(wid * 16 + g * 4 + r) * 136 + col] = f2b(v);
        }
    }
    // no __syncthreads: each wave reads only rows it wrote itself.

#pragma unroll
    for (int nt = 0; nt < 8; ++nt) acc[nt] = (f32x4){0.f, 0.f, 0.f, 0.f};

#pragma unroll
    for (int kt = 0; kt < 4; ++kt) {
        int k0 = kt * 32 + g * 8;
        bf16x8 a = *(const bf16x8*)(&hs[(wid * 16 + m) * 136 + k0]);
#pragma unroll
        for (int nt = 0; nt < 8; ++nt) {
            bf16x8 b = *(const bf16x8*)(&Wt2g[(nt * 16 + m) * 128 + k0]);
            acc[nt] = __builtin_amdgcn_mfma_f32_16x16x32_bf16(a, b, acc[nt], 0, 0, 0);
        }
    }

#pragma unroll
    for (int nt = 0; nt < 8; ++nt) {
        int col = nt * 16 + m;
#pragma unroll
        for (int r = 0; r < 4; ++r) {
            int row2 = row0 + g * 4 + r;
            if (row2 < NN) {
                float v = acc[nt][r];
                if (col < 64) p[(size_t)row2 * 64 + col] = f2b(v);
                else          sf[(size_t)row2 * 64 + (col - 64)] = f2b(v);
            }
        }
    }
}

extern "C" void kernel_launch(void* const* d_in, const int* in_sizes, int n_in,
                              void* d_out, int out_size, void* d_ws, size_t ws_size,
                              hipStream_t stream) {
    const void* x   = d_in[0];
    const int*  ei  = (const int*)d_in[1];
    const void* W1n = d_in[2];
    const void* b1n = d_in[3];
    const void* W1r = d_in[4];
    const void* Wl1 = d_in[5];
    const void* bl1 = d_in[6];
    const void* W2n = d_in[7];
    const void* b2n = d_in[8];
    const void* W2r = d_in[9];
    const void* Wl2 = d_in[10];
    const void* bl2 = d_in[11];

    char* ws = (char*)d_ws;
    // total ~53 MB; p aliases xb (per-row producer/consumer in gemmF only)
    int*            flags = (int*)(ws + 0);                    //      64 B
    int*            cntP  = (int*)(ws + 1024);                 //   6,272 B (padded x16)
    int*            rpack = (int*)(ws + 8192);                 // 400,000 B
    float*          bias1 = (float*)(ws + 409600);             //     512 B
    float*          bias2 = (float*)(ws + 410112);             //     256 B
    unsigned short* Wt1g  = (unsigned short*)(ws + 410368);    //  32,768 B
    unsigned short* Wt2g  = (unsigned short*)(ws + 443136);    //  32,768 B
    int*            csr   = (int*)(ws + 475904);               // 7,225,344 B (NSB*CAP2)
    unsigned short* xb    = (unsigned short*)(ws + 7701248);   // 12,800,000 B
    unsigned short* p     = xb;                                // (row-local alias)
    unsigned short* mean1 = (unsigned short*)(ws + 20501248);  // 12,800,000 B
    unsigned short* sf    = (unsigned short*)(ws + 33301248);  // 12,800,000 B
    int*            ebuf  = (int*)(ws + 46101248);             // 7,225,344 B

    (void)in_sizes; (void)n_in; (void)out_size; (void)ws_size;

    sniff_kernel<<<1, 256, 0, stream>>>(ei, (const unsigned int*)x, flags);
    conv_x_kernel<<<(NN * 8 + 255) / 256, 256, 0, stream>>>(x, flags, (unsigned int*)xb);
    prep_w_kernel<<<2, 256, 0, stream>>>(flags, W1n, W1r, Wl1, b1n, bl1,
                                         W2n, W2r, Wl2, b2n, bl2,
                                         Wt1g, Wt2g, bias1, bias2);
    // super-bucket CSR build (once, shared by both layers)
    hipMemsetAsync(cntP, 0, 6272, stream);
    bscatter_kernel<<<256, 512, 0, stream>>>(ei, flags, cntP, ebuf);
    csr_build_kernel<<<NSB, 512, 0, stream>>>(ebuf, cntP, rpack, csr);
    // layer 1 aggregation (32 dsts per block: 4 waves x 8 slots)
    agg1_kernel<<<(NN + 31) / 32, 256, 0, stream>>>(xb, rpack, csr, (unsigned int*)mean1);
    // fused GEMM (h never leaves the CU)
    gemmF_kernel<<<(NN + 63) / 64, 256, 0, stream>>>(mean1, xb, Wt1g, bias1, Wt2g, p, sf);
    // layer 2 aggregation + epilogue
    agg2_kernel<<<(NN + 31) / 32, 256, 0, stream>>>(p, rpack, csr, (const unsigned int*)sf,
                                                    bias2, flags, d_out);
}

// Round 11
// 268.152 us; speedup vs baseline: 1.0958x; 1.0958x over previous
//
#include <hip/hip_runtime.h>

// GNN_41051297415239: 2-layer GraphSAGE + linear skip on MI355X (gfx950)
// N=100000 nodes, E=1600000 edges, F_IN=64, HID=128, OUT=64
//
// R10 -> R11:
//  1. gemmF: REVERT W1 to LDS staging (R10's global-W1 regressed 43->64us:
//     L1 thrash at 6 blocks/CU, MfmaUtil 3.6%) + prefetch A fragments into
//     registers BEFORE the staging barrier (hides A latency).
//  2. agg gather: oct unroll (8 unconditional row-loads in flight/slot).
//  3. fewer dispatches: cntP zeroing folded into sniff; conv_x + prep_w
//     merged (blocks 0-1 = weights, rest = x). 10 -> 8 dispatches.
//
// Algebra:
//   h   = relu( [mean1 | x] @ [W1n ; W1r+Wl1] + (b1n+bl1) )   (K=128 GEMM)
//   p   = h @ W2n        (project BEFORE aggregating: 64-wide gather)
//   out = mean(p) + h @ (W2r+Wl2) + (b2n+bl2)

#define NN 100000
#define NE 1600000
#define NSB 98          // ceil(NN/1024) super-buckets
#define CAP2 18432      // padded SB capacity (mean 16384, +16 sigma)
#define EPB 6250        // edges per bscatter block (256 blocks)

typedef __attribute__((ext_vector_type(8))) __bf16 bf16x8;
typedef __attribute__((ext_vector_type(4))) float f32x4;

__device__ __forceinline__ float b2f(unsigned short u) {
    unsigned v = ((unsigned)u) << 16;
    float f;
    __builtin_memcpy(&f, &v, 4);
    return f;
}
__device__ __forceinline__ float b2f_lo(unsigned v) {
    unsigned w = v << 16;
    float f;
    __builtin_memcpy(&f, &w, 4);
    return f;
}
__device__ __forceinline__ float b2f_hi(unsigned v) {
    unsigned w = v & 0xFFFF0000u;
    float f;
    __builtin_memcpy(&f, &w, 4);
    return f;
}
__device__ __forceinline__ unsigned short f2b(float f) {
    unsigned u;
    __builtin_memcpy(&u, &f, 4);
    u += 0x7FFFu + ((u >> 16) & 1u);   // round-to-nearest-even
    return (unsigned short)(u >> 16);
}

// flags[0]=1 if edge_index is int64; flags[1]=1 if x/weights are fp32.
// Also zeroes the padded super-bucket cursors (kills a memset dispatch).
__global__ void sniff_kernel(const int* __restrict__ ei,
                             const unsigned int* __restrict__ xw,
                             int* __restrict__ flags, int* __restrict__ cntP) {
    __shared__ int s_or[256];
    __shared__ int s_cnt[256];
    int tid = threadIdx.x;
    if (tid < NSB) cntP[tid * 16] = 0;
    s_or[tid] = ei[2 * tid + 1];
    unsigned e = (xw[tid] >> 7) & 0xFFu;
    s_cnt[tid] = (e > 0x85u) ? 1 : 0;
    __syncthreads();
    for (int s = 128; s > 0; s >>= 1) {
        if (tid < s) { s_or[tid] |= s_or[tid + s]; s_cnt[tid] += s_cnt[tid + s]; }
        __syncthreads();
    }
    if (tid == 0) {
        flags[0] = (s_or[0] == 0) ? 1 : 0;
        flags[1] = (s_cnt[0] >= 32) ? 1 : 0;
    }
}

// Merged prep: blocks 0-1 build combined transposed bf16 weights + biases;
// blocks 2+ canonicalize x -> bf16 (8 elems/thread).
__global__ __launch_bounds__(256) void prep_kernel(
    const void* __restrict__ x, const int* __restrict__ flags,
    const void* W1n, const void* W1r, const void* Wl1,
    const void* b1n, const void* bl1,
    const void* W2n, const void* W2r, const void* Wl2,
    const void* b2n, const void* bl2,
    unsigned short* __restrict__ Wt1g, unsigned short* __restrict__ Wt2g,
    float* __restrict__ bias1, float* __restrict__ bias2,
    unsigned int* __restrict__ xbu) {
    bool fp32 = flags[1] != 0;
    int tid = threadIdx.x;
    if (blockIdx.x >= 2) {
        int t = (blockIdx.x - 2) * 256 + tid;
        if (t >= NN * 8) return;
        if (fp32) {
            const float4* xf = (const float4*)x;
            float4 a = xf[2 * t], b = xf[2 * t + 1];
            uint4 o;
            o.x = f2b(a.x) | ((unsigned)f2b(a.y) << 16);
            o.y = f2b(a.z) | ((unsigned)f2b(a.w) << 16);
            o.z = f2b(b.x) | ((unsigned)f2b(b.y) << 16);
            o.w = f2b(b.z) | ((unsigned)f2b(b.w) << 16);
            ((uint4*)xbu)[t] = o;
        } else {
            ((uint4*)xbu)[t] = ((const uint4*)x)[t];
        }
        return;
    }
    auto rd = [&](const void* p, int i) -> float {
        return fp32 ? ((const float*)p)[i] : b2f(((const unsigned short*)p)[i]);
    };
    if (blockIdx.x == 0) {
        for (int idx = tid; idx < 128 * 128; idx += 256) {
            int k = idx >> 7, c = idx & 127;
            float v = (k < 64) ? rd(W1n, k * 128 + c)
                               : rd(W1r, (k - 64) * 128 + c) + rd(Wl1, (k - 64) * 128 + c);
            Wt1g[c * 128 + k] = f2b(v);
        }
        for (int c = tid; c < 128; c += 256) bias1[c] = rd(b1n, c) + rd(bl1, c);
    } else {
        for (int idx = tid; idx < 128 * 128; idx += 256) {
            int k = idx >> 7, c = idx & 127;
            float v = (c < 64) ? rd(W2n, k * 64 + c)
                               : rd(W2r, k * 64 + (c - 64)) + rd(Wl2, k * 64 + (c - 64));
            Wt2g[c * 128 + k] = f2b(v);
        }
        for (int c = tid; c < 64; c += 256) bias2[c] = rd(b2n, c) + rd(bl2, c);
    }
}

// --- Super-bucket CSR build (once, shared by both agg passes) ---
// cntP: one cursor per 64B line (index sb*16), zeroed by sniff.
// SB sb's window: ebuf/csr [sb*CAP2, sb*CAP2 + cnt_sb).

__global__ __launch_bounds__(512) void bscatter_kernel(
    const int* __restrict__ ei, const int* __restrict__ flags,
    int* __restrict__ cntP, int* __restrict__ ebuf) {
    __shared__ int lh[NSB];     // counts, then rank cursor
    __shared__ int lbase[NSB];  // this block's reserved base within SB
    int t = threadIdx.x;
    if (t < NSB) lh[t] = 0;
    __syncthreads();
    int e0 = blockIdx.x * EPB;
    bool i64 = flags[0] != 0;
    for (int i = t; i < EPB; i += 512) {
        int e = e0 + i;
        int d = i64 ? (int)((const long long*)ei)[NE + e] : ei[NE + e];
        atomicAdd(&lh[d >> 10], 1);
    }
    __syncthreads();
    if (t < NSB) {
        int c = lh[t];
        lbase[t] = c ? atomicAdd(&cntP[t * 16], c) : 0;
        lh[t] = 0;
    }
    __syncthreads();
    for (int i = t; i < EPB; i += 512) {
        int e = e0 + i;
        int s, d;
        if (i64) { const long long* q = (const long long*)ei; s = (int)q[e]; d = (int)q[NE + e]; }
        else     { s = ei[e]; d = ei[NE + e]; }
        int sb = d >> 10;
        int r = lbase[sb] + atomicAdd(&lh[sb], 1);
        if (r < CAP2) ebuf[sb * CAP2 + r] = (s << 10) | (d & 1023);
    }
}

// One block (512 thr) per super-bucket: 1024-counter LDS hist + scan ->
// rpack[d] = (abs_start<<8)|deg, dst-sorted csr into the SB's dense window.
__global__ __launch_bounds__(512) void csr_build_kernel(
    const int* __restrict__ ebuf, const int* __restrict__ cntP,
    int* __restrict__ rpack, int* __restrict__ csr) {
    __shared__ int lcnt[1024];
    __shared__ int lsum[512];
    __shared__ int lcur[1024];
    int t = threadIdx.x, b = blockIdx.x;
    lcnt[t] = 0; lcnt[t + 512] = 0;
    __syncthreads();
    int base = b * CAP2;
    int cnt = min(cntP[b * 16], CAP2);
    for (int i = t; i < cnt; i += 512) atomicAdd(&lcnt[ebuf[base + i] & 1023], 1);
    __syncthreads();
    int c0 = lcnt[2 * t], c1 = lcnt[2 * t + 1];
    lsum[t] = c0 + c1;
    __syncthreads();
    for (int off = 1; off < 512; off <<= 1) {   // Hillis-Steele inclusive
        int v = lsum[t];
        int add = (t >= off) ? lsum[t - off] : 0;
        __syncthreads();
        lsum[t] = v + add;
        __syncthreads();
    }
    int excl = (t == 0) ? 0 : lsum[t - 1];
    int ex0 = excl, ex1 = excl + c0;
    lcur[2 * t] = ex0; lcur[2 * t + 1] = ex1;
    int d0 = b * 1024 + 2 * t;
    if (d0 < NN)     rpack[d0]     = ((base + ex0) << 8) | min(c0, 255);
    if (d0 + 1 < NN) rpack[d0 + 1] = ((base + ex1) << 8) | min(c1, 255);
    __syncthreads();
    for (int i = t; i < cnt; i += 512) {
        int pk = ebuf[base + i];
        int r = atomicAdd(&lcur[pk & 1023], 1);
        csr[base + r] = pk >> 10;
    }
}

// --- Slot-per-dst gather: wave = 8 dsts, 8 lanes/dst, 16B row-loads ---
// Oct loop with UNCONDITIONAL loads: 8 rows in flight per slot.

__device__ __forceinline__ void gather_acc(
    const unsigned short* __restrict__ feat, const int* __restrict__ csr,
    int base, int deg, int fo, float* acc) {
    int t = 0;
    for (; t + 8 <= deg; t += 8) {
        int i0 = csr[base + t],     i1 = csr[base + t + 1];
        int i2 = csr[base + t + 2], i3 = csr[base + t + 3];
        int i4 = csr[base + t + 4], i5 = csr[base + t + 5];
        int i6 = csr[base + t + 6], i7 = csr[base + t + 7];
        bf16x8 v0 = *(const bf16x8*)(feat + (size_t)i0 * 64 + fo);
        bf16x8 v1 = *(const bf16x8*)(feat + (size_t)i1 * 64 + fo);
        bf16x8 v2 = *(const bf16x8*)(feat + (size_t)i2 * 64 + fo);
        bf16x8 v3 = *(const bf16x8*)(feat + (size_t)i3 * 64 + fo);
        bf16x8 v4 = *(const bf16x8*)(feat + (size_t)i4 * 64 + fo);
        bf16x8 v5 = *(const bf16x8*)(feat + (size_t)i5 * 64 + fo);
        bf16x8 v6 = *(const bf16x8*)(feat + (size_t)i6 * 64 + fo);
        bf16x8 v7 = *(const bf16x8*)(feat + (size_t)i7 * 64 + fo);
#pragma unroll
        for (int k = 0; k < 8; ++k)
            acc[k] += (((float)v0[k] + (float)v1[k]) + ((float)v2[k] + (float)v3[k]))
                    + (((float)v4[k] + (float)v5[k]) + ((float)v6[k] + (float)v7[k]));
    }
    for (; t + 4 <= deg; t += 4) {
        int i0 = csr[base + t],     i1 = csr[base + t + 1];
        int i2 = csr[base + t + 2], i3 = csr[base + t + 3];
        bf16x8 v0 = *(const bf16x8*)(feat + (size_t)i0 * 64 + fo);
        bf16x8 v1 = *(const bf16x8*)(feat + (size_t)i1 * 64 + fo);
        bf16x8 v2 = *(const bf16x8*)(feat + (size_t)i2 * 64 + fo);
        bf16x8 v3 = *(const bf16x8*)(feat + (size_t)i3 * 64 + fo);
#pragma unroll
        for (int k = 0; k < 8; ++k)
            acc[k] += ((float)v0[k] + (float)v1[k]) + ((float)v2[k] + (float)v3[k]);
    }
    for (; t < deg; ++t) {
        int i = csr[base + t];
        bf16x8 v = *(const bf16x8*)(feat + (size_t)i * 64 + fo);
#pragma unroll
        for (int k = 0; k < 8; ++k) acc[k] += (float)v[k];
    }
}

// Layer-1 aggregation: write bf16 mean1[N,64].
__global__ __launch_bounds__(256) void agg1_kernel(
    const unsigned short* __restrict__ feat, const int* __restrict__ rpack,
    const int* __restrict__ csr, unsigned int* __restrict__ mean1u) {
    int wid = threadIdx.x >> 6, lane = threadIdx.x & 63;
    int slot = lane >> 3, fo = (lane & 7) * 8;
    int d = (blockIdx.x * 4 + wid) * 8 + slot;
    int dd = min(d, NN - 1);
    int rp = rpack[dd];
    int base = rp >> 8;
    int deg = rp & 255;
    float acc[8];
#pragma unroll
    for (int k = 0; k < 8; ++k) acc[k] = 0.f;
    gather_acc(feat, csr, base, deg, fo, acc);
    if (d < NN) {
        float r = 1.0f / fmaxf((float)deg, 1.0f);
        uint4 o;
        o.x = f2b(acc[0] * r) | ((unsigned)f2b(acc[1] * r) << 16);
        o.y = f2b(acc[2] * r) | ((unsigned)f2b(acc[3] * r) << 16);
        o.z = f2b(acc[4] * r) | ((unsigned)f2b(acc[5] * r) << 16);
        o.w = f2b(acc[6] * r) | ((unsigned)f2b(acc[7] * r) << 16);
        *(uint4*)(mean1u + (size_t)d * 32 + (lane & 7) * 4) = o;
    }
}

// Layer-2 aggregation fused with final epilogue:
// out = mean(p) + sf + bias2  (store fp32 or bf16 per flags[1]).
__global__ __launch_bounds__(256) void agg2_kernel(
    const unsigned short* __restrict__ p, const int* __restrict__ rpack,
    const int* __restrict__ csr, const unsigned int* __restrict__ sfu,
    const float* __restrict__ bias2, const int* __restrict__ flags,
    void* __restrict__ out) {
    int wid = threadIdx.x >> 6, lane = threadIdx.x & 63;
    int slot = lane >> 3, fo = (lane & 7) * 8;
    int d = (blockIdx.x * 4 + wid) * 8 + slot;
    int dd = min(d, NN - 1);
    int rp = rpack[dd];
    int base = rp >> 8;
    int deg = rp & 255;
    float acc[8];
#pragma unroll
    for (int k = 0; k < 8; ++k) acc[k] = 0.f;
    gather_acc(p, csr, base, deg, fo, acc);
    if (d < NN) {
        float r = 1.0f / fmaxf((float)deg, 1.0f);
        uint4 sv = *(const uint4*)(sfu + (size_t)d * 32 + (lane & 7) * 4);
        float4 bA = *(const float4*)(bias2 + fo);
        float4 bB = *(const float4*)(bias2 + fo + 4);
        float v0 = acc[0] * r + b2f_lo(sv.x) + bA.x;
        float v1 = acc[1] * r + b2f_hi(sv.x) + bA.y;
        float v2 = acc[2] * r + b2f_lo(sv.y) + bA.z;
        float v3 = acc[3] * r + b2f_hi(sv.y) + bA.w;
        float v4 = acc[4] * r + b2f_lo(sv.z) + bB.x;
        float v5 = acc[5] * r + b2f_hi(sv.z) + bB.y;
        float v6 = acc[6] * r + b2f_lo(sv.w) + bB.z;
        float v7 = acc[7] * r + b2f_hi(sv.w) + bB.w;
        if (flags[1]) {
            float* op = (float*)out + (size_t)d * 64 + fo;
            *(float4*)op = make_float4(v0, v1, v2, v3);
            *(float4*)(op + 4) = make_float4(v4, v5, v6, v7);
        } else {
            uint4 o;
            o.x = f2b(v0) | ((unsigned)f2b(v1) << 16);
            o.y = f2b(v2) | ((unsigned)f2b(v3) << 16);
            o.z = f2b(v4) | ((unsigned)f2b(v5) << 16);
            o.w = f2b(v6) | ((unsigned)f2b(v7) << 16);
            *(uint4*)((unsigned int*)out + (size_t)d * 32 + (lane & 7) * 4) = o;
        }
    }
}

// Fused GEMM (R9 structure + A-prefetch): phase 1 h = relu([mean1|xb]@W1t
// + b1) with W1 staged in LDS (A fragments prefetched into registers
// BEFORE the staging barrier); h -> per-wave LDS tile (no barrier);
// phase 2 p = h@W2n, sf = h@(W2r+Wl2) with W2 fragments from global.
__global__ __launch_bounds__(256) void gemmF_kernel(
    const unsigned short* __restrict__ mean1,
    const unsigned short* __restrict__ xb,
    const unsigned short* __restrict__ Wt1g, const float* __restrict__ bias1,
    const unsigned short* __restrict__ Wt2g,
    unsigned short* __restrict__ p, unsigned short* __restrict__ sf) {
    __shared__ unsigned short Wt[128 * 136];   // W1 combined (transposed)
    __shared__ unsigned short hs[64 * 136];    // h tile: 64 rows x 128 cols
    int tid = threadIdx.x;
    int wid = tid >> 6, lane = tid & 63;
    int m = lane & 15, g = lane >> 4;
    int row0 = blockIdx.x * 64 + wid * 16;
    int arow = min(row0 + m, NN - 1);

    // prefetch A fragments (latency hidden behind Wt staging + barrier)
    bf16x8 a_frag[4];
#pragma unroll
    for (int kt = 0; kt < 4; ++kt) {
        int k0 = kt * 32 + g * 8;
        a_frag[kt] = (k0 < 64)
            ? *(const bf16x8*)(mean1 + (size_t)arow * 64 + k0)
            : *(const bf16x8*)(xb + (size_t)arow * 64 + (k0 - 64));
    }

    for (int idx = tid; idx < 2048; idx += 256) {
        int c = idx >> 4, ch = idx & 15;
        *(bf16x8*)&Wt[c * 136 + ch * 8] = *(const bf16x8*)&Wt1g[c * 128 + ch * 8];
    }
    __syncthreads();

    f32x4 acc[8];
#pragma unroll
    for (int nt = 0; nt < 8; ++nt) acc[nt] = (f32x4){0.f, 0.f, 0.f, 0.f};

#pragma unroll
    for (int kt = 0; kt < 4; ++kt) {
        int k0 = kt * 32 + g * 8;
#pragma unroll
        for (int nt = 0; nt < 8; ++nt) {
            bf16x8 b = *(const bf16x8*)(&Wt[(nt * 16 + m) * 136 + k0]);
            acc[nt] = __builtin_amdgcn_mfma_f32_16x16x32_bf16(a_frag[kt], b, acc[nt], 0, 0, 0);
        }
    }

    // phase-1 epilogue: relu+bias -> hs (wave's own 16-row slice)
#pragma unroll
    for (int nt = 0; nt < 8; ++nt) {
        int col = nt * 16 + m;
        float bias = bias1[col];
#pragma unroll
        for (int r = 0; r < 4; ++r) {
            float v = fmaxf(acc[nt][r] + bias, 0.0f);
            hs[(wid * 16 + g * 4 + r) * 136 + col] = f2b(v);
        }
    }
    // no __syncthreads: each wave reads only rows it wrote itself.

#pragma unroll
    for (int nt = 0; nt < 8; ++nt) acc[nt] = (f32x4){0.f, 0.f, 0.f, 0.f};

#pragma unroll
    for (int kt = 0; kt < 4; ++kt) {
        int k0 = kt * 32 + g * 8;
        bf16x8 a = *(const bf16x8*)(&hs[(wid * 16 + m) * 136 + k0]);
#pragma unroll
        for (int nt = 0; nt < 8; ++nt) {
            bf16x8 b = *(const bf16x8*)(&Wt2g[(nt * 16 + m) * 128 + k0]);
            acc[nt] = __builtin_amdgcn_mfma_f32_16x16x32_bf16(a, b, acc[nt], 0, 0, 0);
        }
    }

#pragma unroll
    for (int nt = 0; nt < 8; ++nt) {
        int col = nt * 16 + m;
#pragma unroll
        for (int r = 0; r < 4; ++r) {
            int row2 = row0 + g * 4 + r;
            if (row2 < NN) {
                float v = acc[nt][r];
                if (col < 64) p[(size_t)row2 * 64 + col] = f2b(v);
                else          sf[(size_t)row2 * 64 + (col - 64)] = f2b(v);
            }
        }
    }
}

extern "C" void kernel_launch(void* const* d_in, const int* in_sizes, int n_in,
                              void* d_out, int out_size, void* d_ws, size_t ws_size,
                              hipStream_t stream) {
    const void* x   = d_in[0];
    const int*  ei  = (const int*)d_in[1];
    const void* W1n = d_in[2];
    const void* b1n = d_in[3];
    const void* W1r = d_in[4];
    const void* Wl1 = d_in[5];
    const void* bl1 = d_in[6];
    const void* W2n = d_in[7];
    const void* b2n = d_in[8];
    const void* W2r = d_in[9];
    const void* Wl2 = d_in[10];
    const void* bl2 = d_in[11];

    char* ws = (char*)d_ws;
    // total ~53 MB; p aliases xb (block-local producer/consumer in gemmF)
    int*            flags = (int*)(ws + 0);                    //      64 B
    int*            cntP  = (int*)(ws + 1024);                 //   6,272 B (padded x16)
    int*            rpack = (int*)(ws + 8192);                 // 400,000 B
    float*          bias1 = (float*)(ws + 409600);             //     512 B
    float*          bias2 = (float*)(ws + 410112);             //     256 B
    unsigned short* Wt1g  = (unsigned short*)(ws + 410368);    //  32,768 B
    unsigned short* Wt2g  = (unsigned short*)(ws + 443136);    //  32,768 B
    int*            csr   = (int*)(ws + 475904);               // 7,225,344 B (NSB*CAP2)
    unsigned short* xb    = (unsigned short*)(ws + 7701248);   // 12,800,000 B
    unsigned short* p     = xb;                                // (row-local alias)
    unsigned short* mean1 = (unsigned short*)(ws + 20501248);  // 12,800,000 B
    unsigned short* sf    = (unsigned short*)(ws + 33301248);  // 12,800,000 B
    int*            ebuf  = (int*)(ws + 46101248);             // 7,225,344 B

    (void)in_sizes; (void)n_in; (void)out_size; (void)ws_size;

    sniff_kernel<<<1, 256, 0, stream>>>(ei, (const unsigned int*)x, flags, cntP);
    prep_kernel<<<2 + (NN * 8 + 255) / 256, 256, 0, stream>>>(
        x, flags, W1n, W1r, Wl1, b1n, bl1, W2n, W2r, Wl2, b2n, bl2,
        Wt1g, Wt2g, bias1, bias2, (unsigned int*)xb);
    // super-bucket CSR build (once, shared by both layers)
    bscatter_kernel<<<256, 512, 0, stream>>>(ei, flags, cntP, ebuf);
    csr_build_kernel<<<NSB, 512, 0, stream>>>(ebuf, cntP, rpack, csr);
    // layer 1 aggregation (32 dsts per block: 4 waves x 8 slots)
    agg1_kernel<<<(NN + 31) / 32, 256, 0, stream>>>(xb, rpack, csr, (unsigned int*)mean1);
    // fused GEMM (h never leaves the CU)
    gemmF_kernel<<<(NN + 63) / 64, 256, 0, stream>>>(mean1, xb, Wt1g, bias1, Wt2g, p, sf);
    // layer 2 aggregation + epilogue
    agg2_kernel<<<(NN + 31) / 32, 256, 0, stream>>>(p, rpack, csr, (const unsigned int*)sf,
                                                    bias2, flags, d_out);
}